// Round 1
// baseline (95.888 us; speedup 1.0000x reference)
//
#include <hip/hip_runtime.h>

#define CDIM 128
#define HDIM 128

// ---------------------------------------------------------------------------
// Kernel A: per-node 2-layer MLP -> two scalars per node (s_q, s_k).
// Block = 256 threads (4 waves), tile = 32 nodes. Wave w owns rows 8w..8w+7,
// lane l owns output columns {2l, 2l+1}. Register blocking: 16 acc per lane.
// ---------------------------------------------------------------------------
__global__ __launch_bounds__(256) void node_kernel(
    const float* __restrict__ x,
    const float* __restrict__ W1, const float* __restrict__ b1,
    const float* __restrict__ W2, const float* __restrict__ b2,
    const float* __restrict__ We,
    float2* __restrict__ sqk, int N)
{
    __shared__ float xs[32 * CDIM];
    __shared__ float hs[32 * HDIM];

    const int tid = threadIdx.x;
    const int w = tid >> 6;        // wave 0..3
    const int l = tid & 63;        // lane
    const int n0 = blockIdx.x * 32;

    // ---- stage x tile (32 rows x 128 f32) via float4, zero-pad tail rows ----
    const float4* xg = (const float4*)x;
    const int base4 = n0 * (CDIM / 4);       // float4 index of tile start
    const int tot4 = N * (CDIM / 4);
    for (int k = tid; k < 32 * (CDIM / 4); k += 256) {
        float4 v = make_float4(0.f, 0.f, 0.f, 0.f);
        if (base4 + k < tot4) v = xg[base4 + k];
        ((float4*)xs)[k] = v;
    }
    __syncthreads();

    const int j0 = 2 * l;
    const float2 wq = *(const float2*)&We[j0];
    const float2 wk = *(const float2*)&We[HDIM + j0];
    const float2 bias1 = *(const float2*)&b1[j0];
    const float2 bias2 = *(const float2*)&b2[j0];

    float2 acc[8];
#pragma unroll
    for (int r = 0; r < 8; r++) acc[r] = make_float2(0.f, 0.f);

    // ---- layer 1: h1 = relu(x @ W1 + b1) ----
    const float* xrow = &xs[(8 * w) * CDIM];
    for (int i0 = 0; i0 < CDIM; i0 += 4) {
        float2 wrow[4];
#pragma unroll
        for (int k = 0; k < 4; k++)
            wrow[k] = *(const float2*)&W1[(i0 + k) * HDIM + j0];
#pragma unroll
        for (int r = 0; r < 8; r++) {
            float4 xv = *(const float4*)&xrow[r * CDIM + i0];
            acc[r].x = fmaf(xv.x, wrow[0].x, acc[r].x);
            acc[r].y = fmaf(xv.x, wrow[0].y, acc[r].y);
            acc[r].x = fmaf(xv.y, wrow[1].x, acc[r].x);
            acc[r].y = fmaf(xv.y, wrow[1].y, acc[r].y);
            acc[r].x = fmaf(xv.z, wrow[2].x, acc[r].x);
            acc[r].y = fmaf(xv.z, wrow[2].y, acc[r].y);
            acc[r].x = fmaf(xv.w, wrow[3].x, acc[r].x);
            acc[r].y = fmaf(xv.w, wrow[3].y, acc[r].y);
        }
    }
    // bias + relu -> hs (wave-private rows, no cross-wave barrier needed)
#pragma unroll
    for (int r = 0; r < 8; r++) {
        float hx = fmaxf(acc[r].x + bias1.x, 0.f);
        float hy = fmaxf(acc[r].y + bias1.y, 0.f);
        *(float2*)&hs[(8 * w + r) * HDIM + j0] = make_float2(hx, hy);
        acc[r] = make_float2(0.f, 0.f);
    }

    // ---- layer 2: h2 = relu(h1 @ W2 + b2) ----
    const float* hrow = &hs[(8 * w) * HDIM];
    for (int i0 = 0; i0 < HDIM; i0 += 4) {
        float2 wrow[4];
#pragma unroll
        for (int k = 0; k < 4; k++)
            wrow[k] = *(const float2*)&W2[(i0 + k) * HDIM + j0];
#pragma unroll
        for (int r = 0; r < 8; r++) {
            float4 xv = *(const float4*)&hrow[r * HDIM + i0];
            acc[r].x = fmaf(xv.x, wrow[0].x, acc[r].x);
            acc[r].y = fmaf(xv.x, wrow[0].y, acc[r].y);
            acc[r].x = fmaf(xv.y, wrow[1].x, acc[r].x);
            acc[r].y = fmaf(xv.y, wrow[1].y, acc[r].y);
            acc[r].x = fmaf(xv.z, wrow[2].x, acc[r].x);
            acc[r].y = fmaf(xv.z, wrow[2].y, acc[r].y);
            acc[r].x = fmaf(xv.w, wrow[3].x, acc[r].x);
            acc[r].y = fmaf(xv.w, wrow[3].y, acc[r].y);
        }
    }

    // ---- scores: s_q = h2 . Wq, s_k = h2 . Wk, wave-wide reduce ----
#pragma unroll
    for (int r = 0; r < 8; r++) {
        float hx = fmaxf(acc[r].x + bias2.x, 0.f);
        float hy = fmaxf(acc[r].y + bias2.y, 0.f);
        float pq = hx * wq.x + hy * wq.y;
        float pk = hx * wk.x + hy * wk.y;
#pragma unroll
        for (int s = 1; s < 64; s <<= 1) {
            pq += __shfl_xor(pq, s, 64);
            pk += __shfl_xor(pk, s, 64);
        }
        int n = n0 + 8 * w + r;
        if (l == 0 && n < N) sqk[n] = make_float2(pq, pk);
    }
}

// ---------------------------------------------------------------------------
// Kernel B: per-edge scores + float-cast copy of edge_index_neg.
// out[0..E)    = s_q[pos_src] + s_k[pos_dst] + be
// out[E..2E)   = s_q[neg_src] + s_k[neg_dst] + be
// out[2E..3E)  = (float) neg_src
// out[3E..4E)  = (float) neg_dst
// ---------------------------------------------------------------------------
__global__ __launch_bounds__(256) void edge_kernel(
    const int* __restrict__ eip, const int* __restrict__ ein,
    const float2* __restrict__ sqk, const float* __restrict__ be_p,
    float* __restrict__ out, int E)
{
    const float be = be_p[0];
    const int stride = gridDim.x * blockDim.x;
    for (int e = blockIdx.x * blockDim.x + threadIdx.x; e < E; e += stride) {
        int ps = eip[e];
        int pd = eip[E + e];
        int ns = ein[e];
        int nd = ein[E + e];
        float2 a = sqk[ps];
        float2 b = sqk[pd];
        float2 c = sqk[ns];
        float2 d = sqk[nd];
        out[e]         = a.x + b.y + be;
        out[E + e]     = c.x + d.y + be;
        out[2 * E + e] = (float)ns;
        out[3 * E + e] = (float)nd;
    }
}

extern "C" void kernel_launch(void* const* d_in, const int* in_sizes, int n_in,
                              void* d_out, int out_size, void* d_ws, size_t ws_size,
                              hipStream_t stream) {
    const float* x   = (const float*)d_in[0];
    const int*   eip = (const int*)d_in[1];
    const int*   ein = (const int*)d_in[2];
    // d_in[3] = batch (unused by the reference outputs)
    const float* W1  = (const float*)d_in[4];
    const float* b1  = (const float*)d_in[5];
    const float* W2  = (const float*)d_in[6];
    const float* b2  = (const float*)d_in[7];
    const float* We  = (const float*)d_in[8];
    const float* be  = (const float*)d_in[9];

    const int N = in_sizes[0] / CDIM;
    const int E = in_sizes[1] / 2;

    float2* sqk = (float2*)d_ws;   // N * 8 bytes

    const int nblk = (N + 31) / 32;
    node_kernel<<<nblk, 256, 0, stream>>>(x, W1, b1, W2, b2, We, sqk, N);
    edge_kernel<<<2048, 256, 0, stream>>>(eip, ein, sqk, be, (float*)d_out, E);
}

// Round 2
// 56.179 us; speedup vs baseline: 1.7068x; 1.7068x over previous
//
#include <hip/hip_runtime.h>

#define CDIM 128
#define HDIM 128
#define MT   64     // rows per block
#define LDP  136    // padded LDS row stride (bf16 elems): 272B -> 2-way conflicts only

typedef short bf16x8 __attribute__((ext_vector_type(8)));
typedef float f32x4  __attribute__((ext_vector_type(4)));

// fp32 -> bf16 bits, round-to-nearest-even (matches np/jax for normal values)
static __device__ __forceinline__ short f2bf(float f) {
    union { float f; unsigned u; } v; v.f = f;
    unsigned r = v.u + 0x7FFFu + ((v.u >> 16) & 1u);
    return (short)(r >> 16);
}

// ---------------------------------------------------------------------------
// Node pass: h2 = relu(relu(x@W1+b1)@W2+b2); sqk[n] = (h2[n].Wq, h2[n].Wk)
// Block = 256 thr (4 waves), 64 rows. MFMA 16x16x32 bf16, fp32 accum.
// A-frag: row = lane&15, k = 8*(lane>>4)+j (A and B share the k-map, so any
// HW k-permutation cancels). C/D: col = lane&15, row = (lane>>4)*4 + reg.
// ---------------------------------------------------------------------------
__global__ __launch_bounds__(256) void node_mfma(
    const float* __restrict__ x,
    const float* __restrict__ W1, const float* __restrict__ b1,
    const float* __restrict__ W2, const float* __restrict__ b2,
    const float* __restrict__ We,
    float2* __restrict__ sqk, int N)
{
    __shared__ short wt[HDIM][LDP];  // W^T (bf16): wt[n][k]
    __shared__ short hs[MT][LDP];    // h1 (bf16), block-local rows

    const int tid = threadIdx.x;
    const int w   = tid >> 6;
    const int l   = tid & 63;
    const int lr  = l & 15;          // fragment left index (row of A / col of B&D)
    const int lg  = l >> 4;          // k-group
    const int rowg0 = blockIdx.x * MT + w * 16;  // wave's first global row
    const int rowb0 = w * 16;                    // wave's first block-local row

    // ---- stage wt = W1^T (bf16); W1 is [K][N] row-major ----
    for (int idx = tid; idx < CDIM * HDIM; idx += 256) {
        int k = idx >> 7, n = idx & (HDIM - 1);
        wt[n][k] = f2bf(W1[idx]);
    }
    __syncthreads();

    // ---- layer 1: A direct from global x (fp32 -> bf16 on the fly) ----
    f32x4 acc[8];
#pragma unroll
    for (int f = 0; f < 8; f++) acc[f] = (f32x4){0.f, 0.f, 0.f, 0.f};

    const int arow = rowg0 + lr;
#pragma unroll
    for (int ks = 0; ks < 4; ks++) {
        bf16x8 a;
        if (arow < N) {
            const float* xp = &x[arow * CDIM + ks * 32 + lg * 8];
            float4 v0 = *(const float4*)xp;
            float4 v1 = *(const float4*)(xp + 4);
            a[0] = f2bf(v0.x); a[1] = f2bf(v0.y); a[2] = f2bf(v0.z); a[3] = f2bf(v0.w);
            a[4] = f2bf(v1.x); a[5] = f2bf(v1.y); a[6] = f2bf(v1.z); a[7] = f2bf(v1.w);
        } else {
            a = (bf16x8){0, 0, 0, 0, 0, 0, 0, 0};
        }
#pragma unroll
        for (int f = 0; f < 8; f++) {
            bf16x8 b = *(const bf16x8*)&wt[f * 16 + lr][ks * 32 + lg * 8];
            acc[f] = __builtin_amdgcn_mfma_f32_16x16x32_bf16(a, b, acc[f], 0, 0, 0);
        }
    }

    // ---- h1 = relu(acc + b1) -> hs (bf16) ----
#pragma unroll
    for (int f = 0; f < 8; f++) {
        const int col = f * 16 + lr;
        const float bb = b1[col];
#pragma unroll
        for (int r = 0; r < 4; r++) {
            float h = fmaxf(acc[f][r] + bb, 0.f);
            hs[rowb0 + lg * 4 + r][col] = f2bf(h);
        }
    }
    __syncthreads();   // hs visible; all waves done reading wt(W1)

    // ---- restage wt = W2^T ----
    for (int idx = tid; idx < HDIM * HDIM; idx += 256) {
        int k = idx >> 7, n = idx & (HDIM - 1);
        wt[n][k] = f2bf(W2[idx]);
    }
    __syncthreads();

    // ---- layer 2: A from hs ----
#pragma unroll
    for (int f = 0; f < 8; f++) acc[f] = (f32x4){0.f, 0.f, 0.f, 0.f};

#pragma unroll
    for (int ks = 0; ks < 4; ks++) {
        bf16x8 a = *(const bf16x8*)&hs[rowb0 + lr][ks * 32 + lg * 8];
#pragma unroll
        for (int f = 0; f < 8; f++) {
            bf16x8 b = *(const bf16x8*)&wt[f * 16 + lr][ks * 32 + lg * 8];
            acc[f] = __builtin_amdgcn_mfma_f32_16x16x32_bf16(a, b, acc[f], 0, 0, 0);
        }
    }

    // ---- epilogue: s_q = relu(h2).Wq, s_k = relu(h2).Wk, 16-lane reduce ----
    float pq[4] = {0.f, 0.f, 0.f, 0.f};
    float pk[4] = {0.f, 0.f, 0.f, 0.f};
#pragma unroll
    for (int f = 0; f < 8; f++) {
        const int col = f * 16 + lr;
        const float bb = b2[col];
        const float wq = We[col];
        const float wk = We[HDIM + col];
#pragma unroll
        for (int r = 0; r < 4; r++) {
            float h = fmaxf(acc[f][r] + bb, 0.f);
            pq[r] = fmaf(h, wq, pq[r]);
            pk[r] = fmaf(h, wk, pk[r]);
        }
    }
#pragma unroll
    for (int r = 0; r < 4; r++) {
#pragma unroll
        for (int s = 1; s < 16; s <<= 1) {
            pq[r] += __shfl_xor(pq[r], s, 64);
            pk[r] += __shfl_xor(pk[r], s, 64);
        }
    }
    if (lr == 0) {
#pragma unroll
        for (int r = 0; r < 4; r++) {
            int n = rowg0 + lg * 4 + r;
            if (n < N) sqk[n] = make_float2(pq[r], pk[r]);
        }
    }
}

// ---------------------------------------------------------------------------
// Edge pass: out[0..E) pos scores, [E..2E) neg scores, [2E..4E) float(ein)
// ---------------------------------------------------------------------------
__global__ __launch_bounds__(256) void edge_kernel(
    const int* __restrict__ eip, const int* __restrict__ ein,
    const float2* __restrict__ sqk, const float* __restrict__ be_p,
    float* __restrict__ out, int E)
{
    const float be = be_p[0];
    const int stride = gridDim.x * blockDim.x;
    for (int e = blockIdx.x * blockDim.x + threadIdx.x; e < E; e += stride) {
        int ps = eip[e];
        int pd = eip[E + e];
        int ns = ein[e];
        int nd = ein[E + e];
        float2 a = sqk[ps];
        float2 b = sqk[pd];
        float2 c = sqk[ns];
        float2 d = sqk[nd];
        out[e]         = a.x + b.y + be;
        out[E + e]     = c.x + d.y + be;
        out[2 * E + e] = (float)ns;
        out[3 * E + e] = (float)nd;
    }
}

extern "C" void kernel_launch(void* const* d_in, const int* in_sizes, int n_in,
                              void* d_out, int out_size, void* d_ws, size_t ws_size,
                              hipStream_t stream) {
    const float* x   = (const float*)d_in[0];
    const int*   eip = (const int*)d_in[1];
    const int*   ein = (const int*)d_in[2];
    // d_in[3] = batch (unused by the reference outputs)
    const float* W1  = (const float*)d_in[4];
    const float* b1  = (const float*)d_in[5];
    const float* W2  = (const float*)d_in[6];
    const float* b2  = (const float*)d_in[7];
    const float* We  = (const float*)d_in[8];
    const float* be  = (const float*)d_in[9];

    const int N = in_sizes[0] / CDIM;
    const int E = in_sizes[1] / 2;

    float2* sqk = (float2*)d_ws;   // N * 8 bytes

    const int nblk = (N + MT - 1) / MT;
    node_mfma<<<nblk, 256, 0, stream>>>(x, W1, b1, W2, b2, We, sqk, N);
    edge_kernel<<<2048, 256, 0, stream>>>(eip, ein, sqk, be, (float*)d_out, E);
}

// Round 3
// 36.236 us; speedup vs baseline: 2.6462x; 1.5503x over previous
//
#include <hip/hip_runtime.h>

#define CDIM 128
#define HDIM 128
#define MT   128    // rows per node block
#define LDP  136    // padded LDS row stride (bf16): 272B = 17*16 -> b128-aligned, 2-way conflicts only
#define LIM  40000  // nodes cached in LDS by edge kernel (4B each -> 160000 B)

typedef short bf16x8 __attribute__((ext_vector_type(8)));
typedef float f32x4  __attribute__((ext_vector_type(4)));

// fp32 -> bf16 bits, round-to-nearest-even
static __device__ __forceinline__ short f2bf(float f) {
    union { float f; unsigned u; } v; v.f = f;
    unsigned r = v.u + 0x7FFFu + ((v.u >> 16) & 1u);
    return (short)(r >> 16);
}

// ---------------------------------------------------------------------------
// Prologue: wt1g[n*128+k] = bf16(W1[k][n]) (transposed), same for W2.
// ---------------------------------------------------------------------------
__global__ __launch_bounds__(256) void prep_kernel(
    const float* __restrict__ W1, const float* __restrict__ W2,
    short* __restrict__ wt1g, short* __restrict__ wt2g)
{
    int id = blockIdx.x * 256 + threadIdx.x;          // 0..32767
    const float* src = (id < 16384) ? W1 : W2;
    short* dst = (id < 16384) ? wt1g : wt2g;
    int i = id & 16383;
    int n = i >> 7, k = i & 127;
    dst[i] = f2bf(src[k * HDIM + n]);
}

// ---------------------------------------------------------------------------
// Node pass: h2 = relu(relu(x@W1+b1)@W2+b2); tab[n] = pack(bf16(h2.Wq), bf16(h2.Wk))
// 512 thr (8 waves), 128 rows/block. MFMA 16x16x32 bf16, fp32 accum.
// A-frag: row = lane&15, k = 8*(lane>>4)+j (A and B share the k-map).
// C/D: col = lane&15, row = (lane>>4)*4 + reg.
// ---------------------------------------------------------------------------
__global__ __launch_bounds__(512) void node_mfma(
    const float* __restrict__ x,
    const short* __restrict__ wt1g, const float* __restrict__ b1,
    const short* __restrict__ wt2g, const float* __restrict__ b2,
    const float* __restrict__ We,
    unsigned* __restrict__ tab, int N)
{
    __shared__ short wt[HDIM][LDP];  // W^T (bf16): wt[n][k]
    __shared__ short hs[MT][LDP];    // h1 (bf16), block-local rows

    const int tid = threadIdx.x;
    const int w   = tid >> 6;        // wave 0..7
    const int l   = tid & 63;
    const int lr  = l & 15;
    const int lg  = l >> 4;
    const int rowg0 = blockIdx.x * MT + w * 16;
    const int rowb0 = w * 16;

    // ---- stage W1^T from pre-converted bf16 (vectorized, 4 iters/thread) ----
    for (int idx = tid * 8; idx < CDIM * HDIM; idx += 512 * 8)
        *(bf16x8*)&wt[idx >> 7][idx & 127] = *(const bf16x8*)&wt1g[idx];
    __syncthreads();

    // ---- layer 1: A direct from global x (fp32 -> bf16 on the fly) ----
    f32x4 acc[8];
#pragma unroll
    for (int f = 0; f < 8; f++) acc[f] = (f32x4){0.f, 0.f, 0.f, 0.f};

    const int arow = rowg0 + lr;
#pragma unroll
    for (int ks = 0; ks < 4; ks++) {
        bf16x8 a;
        if (arow < N) {
            const float* xp = &x[arow * CDIM + ks * 32 + lg * 8];
            float4 v0 = *(const float4*)xp;
            float4 v1 = *(const float4*)(xp + 4);
            a[0] = f2bf(v0.x); a[1] = f2bf(v0.y); a[2] = f2bf(v0.z); a[3] = f2bf(v0.w);
            a[4] = f2bf(v1.x); a[5] = f2bf(v1.y); a[6] = f2bf(v1.z); a[7] = f2bf(v1.w);
        } else {
            a = (bf16x8){0, 0, 0, 0, 0, 0, 0, 0};
        }
#pragma unroll
        for (int f = 0; f < 8; f++) {
            bf16x8 b = *(const bf16x8*)&wt[f * 16 + lr][ks * 32 + lg * 8];
            acc[f] = __builtin_amdgcn_mfma_f32_16x16x32_bf16(a, b, acc[f], 0, 0, 0);
        }
    }

    // ---- h1 = relu(acc + b1) -> hs (bf16) ----
#pragma unroll
    for (int f = 0; f < 8; f++) {
        const int col = f * 16 + lr;
        const float bb = b1[col];
#pragma unroll
        for (int r = 0; r < 4; r++) {
            float h = fmaxf(acc[f][r] + bb, 0.f);
            hs[rowb0 + lg * 4 + r][col] = f2bf(h);
        }
        acc[f] = (f32x4){0.f, 0.f, 0.f, 0.f};
    }
    __syncthreads();   // hs visible; all waves done with wt(W1)

    // ---- restage wt = W2^T ----
    for (int idx = tid * 8; idx < HDIM * HDIM; idx += 512 * 8)
        *(bf16x8*)&wt[idx >> 7][idx & 127] = *(const bf16x8*)&wt2g[idx];
    __syncthreads();

    // ---- layer 2: A from hs ----
#pragma unroll
    for (int ks = 0; ks < 4; ks++) {
        bf16x8 a = *(const bf16x8*)&hs[rowb0 + lr][ks * 32 + lg * 8];
#pragma unroll
        for (int f = 0; f < 8; f++) {
            bf16x8 b = *(const bf16x8*)&wt[f * 16 + lr][ks * 32 + lg * 8];
            acc[f] = __builtin_amdgcn_mfma_f32_16x16x32_bf16(a, b, acc[f], 0, 0, 0);
        }
    }

    // ---- epilogue: s_q = relu(h2).Wq, s_k = relu(h2).Wk, 16-lane reduce ----
    float pq[4] = {0.f, 0.f, 0.f, 0.f};
    float pk[4] = {0.f, 0.f, 0.f, 0.f};
#pragma unroll
    for (int f = 0; f < 8; f++) {
        const int col = f * 16 + lr;
        const float bb = b2[col];
        const float wq = We[col];
        const float wk = We[HDIM + col];
#pragma unroll
        for (int r = 0; r < 4; r++) {
            float h = fmaxf(acc[f][r] + bb, 0.f);
            pq[r] = fmaf(h, wq, pq[r]);
            pk[r] = fmaf(h, wk, pk[r]);
        }
    }
#pragma unroll
    for (int r = 0; r < 4; r++) {
#pragma unroll
        for (int s = 1; s < 16; s <<= 1) {
            pq[r] += __shfl_xor(pq[r], s, 64);
            pk[r] += __shfl_xor(pk[r], s, 64);
        }
    }
    if (lr == 0) {
#pragma unroll
        for (int r = 0; r < 4; r++) {
            int n = rowg0 + lg * 4 + r;
            if (n < N) {
                unsigned u = (unsigned)(unsigned short)f2bf(pq[r])
                           | ((unsigned)(unsigned short)f2bf(pk[r]) << 16);
                tab[n] = u;
            }
        }
    }
}

// ---------------------------------------------------------------------------
// Edge pass: LDS-cached score table (nodes < LIM), residual via L2.
// out[0..E) pos, [E..2E) neg, [2E..3E) float(neg_src), [3E..4E) float(neg_dst)
// ---------------------------------------------------------------------------
__global__ __launch_bounds__(1024) void edge_kernel(
    const int* __restrict__ eip, const int* __restrict__ ein,
    const unsigned* __restrict__ tab, const float* __restrict__ be_p,
    float* __restrict__ out, int E)
{
    __shared__ unsigned lt[LIM];     // 160000 B
    const int tid = threadIdx.x;
    const int chunk = (E + gridDim.x - 1) / gridDim.x;
    const int estart = blockIdx.x * chunk;
    const int eend = min(E, estart + chunk);

    // preload first iteration's indices so they fly during staging
    int e = estart + tid;
    bool v = e < eend;
    int ps = 0, pd = 0, ns = 0, nd = 0;
    if (v) { ps = eip[e]; pd = eip[E + e]; ns = ein[e]; nd = ein[E + e]; }

    // stage table (coalesced uint4)
    uint4* lt4 = (uint4*)lt;
    const uint4* tg4 = (const uint4*)tab;
    for (int i = tid; i < LIM / 4; i += 1024) lt4[i] = tg4[i];
    __syncthreads();

    const float be = be_p[0];
    while (v) {
        int e2 = e + 1024;
        bool v2 = e2 < eend;
        int ps2 = 0, pd2 = 0, ns2 = 0, nd2 = 0;
        if (v2) { ps2 = eip[e2]; pd2 = eip[E + e2]; ns2 = ein[e2]; nd2 = ein[E + e2]; }

        unsigned ups = (ps < LIM) ? lt[ps] : tab[ps];
        unsigned upd = (pd < LIM) ? lt[pd] : tab[pd];
        unsigned uns = (ns < LIM) ? lt[ns] : tab[ns];
        unsigned und = (nd < LIM) ? lt[nd] : tab[nd];

        out[e]         = __uint_as_float(ups << 16) + __uint_as_float(upd & 0xFFFF0000u) + be;
        out[E + e]     = __uint_as_float(uns << 16) + __uint_as_float(und & 0xFFFF0000u) + be;
        out[2 * E + e] = (float)ns;
        out[3 * E + e] = (float)nd;

        e = e2; v = v2; ps = ps2; pd = pd2; ns = ns2; nd = nd2;
    }
}

extern "C" void kernel_launch(void* const* d_in, const int* in_sizes, int n_in,
                              void* d_out, int out_size, void* d_ws, size_t ws_size,
                              hipStream_t stream) {
    const float* x   = (const float*)d_in[0];
    const int*   eip = (const int*)d_in[1];
    const int*   ein = (const int*)d_in[2];
    // d_in[3] = batch (unused)
    const float* W1  = (const float*)d_in[4];
    const float* b1  = (const float*)d_in[5];
    const float* W2  = (const float*)d_in[6];
    const float* b2  = (const float*)d_in[7];
    const float* We  = (const float*)d_in[8];
    const float* be  = (const float*)d_in[9];

    const int N = in_sizes[0] / CDIM;
    const int E = in_sizes[1] / 2;

    // workspace layout: [0,200KiB) packed bf16x2 score table; then bf16 weights
    char* ws = (char*)d_ws;
    unsigned* tab  = (unsigned*)ws;                 // N*4 bytes
    short*    wt1g = (short*)(ws + 204800);         // 32768 B
    short*    wt2g = (short*)(ws + 204800 + 32768); // 32768 B

    prep_kernel<<<128, 256, 0, stream>>>(W1, W2, wt1g, wt2g);
    node_mfma<<<(N + MT - 1) / MT, 512, 0, stream>>>(x, wt1g, b1, wt2g, b2, We, tab, N);
    edge_kernel<<<256, 1024, 0, stream>>>(eip, ein, tab, be, (float*)d_out, E);
}